// Round 8
// baseline (113.080 us; speedup 1.0000x reference)
//
#include <hip/hip_runtime.h>

#define NB   4
#define CO   16
#define PH   7
#define PW   7
#define SR   2
#define HH   80
#define WW   80
#define NROI 512
#define CIJ  (CO*PH*PW)   // 784
#define PLANE (HH*WW)     // 6400 floats = 25.6 KB
#define NF4  (PLANE/4)    // 1600

typedef float f4v __attribute__((ext_vector_type(4), aligned(16)));
typedef float f4u __attribute__((ext_vector_type(4), aligned(4)));

typedef __attribute__((address_space(1))) const void gvoid_t;
typedef __attribute__((address_space(3))) void svoid_t;

// Single kernel: one block per (cij, b) unit, 3136 blocks x 256 threads.
//  1. issue global_load_lds DMA for plane (b,cij)  (in flight during step 2)
//  2. in-block ballot-compaction of this batch's ROI indices into LDS
//  3. one __syncthreads (drains DMA, publishes list)
//  4. pair-split gather: lanes (2i,2i+1) handle one ROI, one sy-row each
// No prep kernel, no d_ws. Feat read exactly once (80 MB, sequential).
__global__ __launch_bounds__(256) void psroi_main_kernel(
    const float* __restrict__ feat,   // [B, CIJ, H, W]
    const float* __restrict__ rois,   // [N, 5]
    float* __restrict__ out)          // [N, CO, PH, PW]
{
    __shared__ __align__(16) float sp[PLANE];
    __shared__ unsigned short list[NROI];
    __shared__ int cnt;

    int u   = blockIdx.x;       // cij*4 + b
    int cij = u >> 2;
    int b   = u & 3;
    int rem = cij % (PH * PW);
    int i = rem / PW;
    int j = rem % PW;
    int n = threadIdx.x;
    int lane = n & 63;

    // ---- 1. stage plane (b, cij) via global_load_lds (16B/lane DMA) ----
    const f4v* src = (const f4v*)(feat + ((size_t)b * CIJ + (size_t)cij) * PLANE);
    int wbase = n & ~63;        // wave-uniform element base (f4 units)
    #pragma unroll
    for (int it = 0; it < 6; ++it) {
        const f4v* g = src + it * 256 + n;
        float* l = sp + (size_t)(it * 256 + wbase) * 4;
        __builtin_amdgcn_global_load_lds((gvoid_t*)g, (svoid_t*)l, 16, 0, 0);
    }
    if (n < 64) {               // tail 1536..1599 (wave 0)
        const f4v* g = src + 1536 + n;
        float* l = sp + (size_t)1536 * 4;
        __builtin_amdgcn_global_load_lds((gvoid_t*)g, (svoid_t*)l, 16, 0, 0);
    }

    // ---- 2. compact this batch's ROI indices (overlaps DMA) ----
    if (n == 0) cnt = 0;
    __syncthreads();            // cnt=0 visible (DMA drain here is harmless)
    #pragma unroll
    for (int pass = 0; pass < 2; ++pass) {
        int m = n + pass * 256;
        bool hit = ((int)rois[m * 5] == b);
        unsigned long long mask = __ballot(hit);
        int before = __popcll(mask & ((1ULL << lane) - 1ULL));
        int total  = __popcll(mask);
        int wb = 0;
        if (lane == 0 && total) wb = atomicAdd(&cnt, total);
        wb = __shfl(wb, 0);
        if (hit) list[wb + before] = (unsigned short)m;
    }

    __syncthreads();            // DMA drained + list/cnt published
    int count = cnt;

    // ---- 4. gather: thread-pair per ROI, one sy-row per lane ----
    int sy = n & 1;
    float sy_off = ((float)sy + 0.5f) * (1.0f / SR);

    for (int t = (n >> 1); t < count; t += 128) {
        int m = (int)list[t];
        f4u g = *(const f4u*)(rois + m * 5 + 1);   // x1,y1,x2,y2 (L1-hot)
        float x1 = g.x * (float)WW;
        float y1 = g.y * (float)HH;
        float bin_w = fmaxf(g.z * (float)WW - x1, 0.1f) * (1.0f / PW);
        float bin_h = fmaxf(g.w * (float)HH - y1, 0.1f) * (1.0f / PH);

        float ys = y1 + ((float)i + sy_off) * bin_h;
        bool ymask = (ys >= -1.0f) && (ys <= (float)HH);
        float yc = fminf(fmaxf(ys, 0.0f), (float)(HH - 1));
        int   y0 = (int)floorf(yc);
        int   y1i = min(y0 + 1, HH - 1);
        float ly = yc - (float)y0, hy = 1.0f - ly;

        float partial = 0.0f;
        #pragma unroll
        for (int sx = 0; sx < SR; ++sx) {
            float xs = x1 + ((float)j + ((float)sx + 0.5f) * (1.0f / SR)) * bin_w;
            bool xmask = (xs >= -1.0f) && (xs <= (float)WW);
            float xc = fminf(fmaxf(xs, 0.0f), (float)(WW - 1));
            int   x0 = (int)floorf(xc);
            int   x0c = min(x0, WW - 2);   // x0==79 -> lx==0, shifted pair exact
            bool  sh = (x0 != x0c);
            float lx = xc - (float)x0, hx = 1.0f - lx;

            float t0 = sp[y0  * WW + x0c], t1 = sp[y0  * WW + x0c + 1];
            float b0 = sp[y1i * WW + x0c], b1 = sp[y1i * WW + x0c + 1];

            float v00 = sh ? t1 : t0;
            float v10 = sh ? b1 : b0;
            float v = (v00 * hx + t1 * lx) * hy + (v10 * hx + b1 * lx) * ly;
            if (ymask && xmask) partial += v;
        }

        float other = __shfl_xor(partial, 1);
        if (sy == 0)
            out[(size_t)m * CIJ + cij] = (partial + other) * 0.25f;
    }
}

extern "C" void kernel_launch(void* const* d_in, const int* in_sizes, int n_in,
                              void* d_out, int out_size, void* d_ws, size_t ws_size,
                              hipStream_t stream)
{
    const float* feat = (const float*)d_in[0];
    const float* rois = (const float*)d_in[1];
    float* out = (float*)d_out;

    psroi_main_kernel<<<CIJ * NB, 256, 0, stream>>>(feat, rois, out);
}